// Round 1
// baseline (318.907 us; speedup 1.0000x reference)
//
#include <hip/hip_runtime.h>
#include <stdint.h>
#include <math.h>

#define ENC 512
#define NSTEPS 5
#define SIMS_BLOCKS 1024
#define NWAVES (SIMS_BLOCKS * 256 / 64)   // 4096 waves

struct SelState {
  int   taken[8];     // selected (taken) card ids, -1 = empty
  int   takenCount;
  int   active;
  int   outIdx[8];    // per-step output indices (-1 when not taken)
  float tlp;          // total log prob
};

// ---------------- Threefry-2x32-20 (exact JAX implementation) ----------------
__host__ __device__ __forceinline__ void tf2x32(uint32_t k0, uint32_t k1,
                                                uint32_t x0, uint32_t x1,
                                                uint32_t& o0, uint32_t& o1) {
  uint32_t ks0 = k0, ks1 = k1, ks2 = k0 ^ k1 ^ 0x1BD11BDAu;
  uint32_t ks[3] = {ks0, ks1, ks2};
  const uint32_t R0[4] = {13u, 15u, 26u, 6u};
  const uint32_t R1[4] = {17u, 29u, 16u, 24u};
  x0 += ks0; x1 += ks1;
#pragma unroll
  for (int i = 0; i < 5; ++i) {
    const uint32_t* r = (i & 1) ? R1 : R0;
#pragma unroll
    for (int j = 0; j < 4; ++j) {
      x0 += x1;
      x1 = (x1 << r[j]) | (x1 >> (32u - r[j]));
      x1 ^= x0;
    }
    x0 += ks[(i + 1) % 3];
    x1 += ks[(i + 2) % 3] + (uint32_t)(i + 1);
  }
  o0 = x0; o1 = x1;
}

// ---------------- XLA-matching activations ----------------
// XLA F32 tanh: |x|<0.0004 -> x ; else Eigen rational poly on clamped input.
__device__ __forceinline__ float xla_tanh(float x) {
  if (fabsf(x) < 0.0004f) return x;
  const float kLim = 7.90531110763549805f;
  float cx = fminf(fmaxf(x, -kLim), kLim);
  float x2 = cx * cx;
  float p = -2.76076847742355e-16f;
  p = fmaf(p, x2, 2.00018790482477e-13f);
  p = fmaf(p, x2, -8.60467152213735e-11f);
  p = fmaf(p, x2, 5.12229709037114e-08f);
  p = fmaf(p, x2, 1.48572235717979e-05f);
  p = fmaf(p, x2, 6.37261928875436e-04f);
  p = fmaf(p, x2, 4.89352455891786e-03f);
  p = cx * p;
  float q = 1.19825839466702e-06f;
  q = fmaf(q, x2, 1.18534705686654e-04f);
  q = fmaf(q, x2, 2.26843463243900e-03f);
  q = fmaf(q, x2, 4.89352518554385e-03f);
  return p / q;
}
// XLA logistic expansion: 0.5 + 0.5*tanh(0.5*x)
__device__ __forceinline__ float xla_sigmoid(float x) {
  return 0.5f * xla_tanh(0.5f * x) + 0.5f;
}

// ---------------- kernels ----------------
__global__ void init_kernel(float* __restrict__ Z, SelState* st) {
  int t = threadIdx.x;
  if (t < ENC) Z[t] = 0.0f;
  if (t == 0) {
    for (int i = 0; i < 8; ++i) st->taken[i] = -1;
    st->takenCount = 0;
    st->active = 1;
    st->tlp = 0.0f;
    for (int i = 0; i < 8; ++i) st->outIdx[i] = -1;
  }
}

// vout[r] = dot(W[r,:512], vin) + b[r], 512 rows. Wave-per-row.
__global__ void matvec512(const float* __restrict__ W, const float* __restrict__ b,
                          const float* __restrict__ vin, float* __restrict__ vout) {
  int tid = blockIdx.x * blockDim.x + threadIdx.x;
  int wave = tid >> 6;
  int lane = tid & 63;
  if (wave >= ENC) return;
  const float4* Wr = (const float4*)(W + (size_t)wave * ENC);
  const float4* vi = (const float4*)vin;
  float4 a0 = Wr[lane * 2 + 0], a1 = Wr[lane * 2 + 1];
  float4 v0 = vi[lane * 2 + 0], v1 = vi[lane * 2 + 1];
  float acc = a0.x * v0.x + a0.y * v0.y + a0.z * v0.z + a0.w * v0.w +
              a1.x * v1.x + a1.y * v1.y + a1.z * v1.z + a1.w * v1.w;
#pragma unroll
  for (int k = 1; k < 64; k <<= 1) acc += __shfl_xor(acc, k, 64);
  if (lane == 0) vout[wave] = acc + b[wave];
}

// One LSTM step. Block per output column j (512 blocks, 256 threads).
// Gate order i,f,g,o (PyTorch). gates = ((x@Wih.T + b_ih) + h@Whh.T) + b_hh
__global__ void lstm_step_kernel(const float* __restrict__ w_ih, const float* __restrict__ w_hh,
                                 const float* __restrict__ b_ih, const float* __restrict__ b_hh,
                                 const float* __restrict__ x, const float* __restrict__ h_in,
                                 const float* __restrict__ c_in,
                                 float* __restrict__ h_out, float* __restrict__ c_out) {
  __shared__ float gates[4];
  int j = blockIdx.x;
  int g = threadIdx.x >> 6;
  int lane = threadIdx.x & 63;
  size_t row = (size_t)(g * ENC + j) * ENC;
  const float4* wi = (const float4*)(w_ih + row);
  const float4* wh = (const float4*)(w_hh + row);
  const float4* xv = (const float4*)x;
  const float4* hv = (const float4*)h_in;
  float4 wa = wi[lane * 2 + 0], wb = wi[lane * 2 + 1];
  float4 xa = xv[lane * 2 + 0], xb = xv[lane * 2 + 1];
  float accI = wa.x * xa.x + wa.y * xa.y + wa.z * xa.z + wa.w * xa.w +
               wb.x * xb.x + wb.y * xb.y + wb.z * xb.z + wb.w * xb.w;
  float4 va = wh[lane * 2 + 0], vb = wh[lane * 2 + 1];
  float4 ha = hv[lane * 2 + 0], hb = hv[lane * 2 + 1];
  float accH = va.x * ha.x + va.y * ha.y + va.z * ha.z + va.w * ha.w +
               vb.x * hb.x + vb.y * hb.y + vb.z * hb.z + vb.w * hb.w;
#pragma unroll
  for (int k = 1; k < 64; k <<= 1) {
    accI += __shfl_xor(accI, k, 64);
    accH += __shfl_xor(accH, k, 64);
  }
  if (lane == 0) gates[g] = ((accI + b_ih[g * ENC + j]) + accH) + b_hh[g * ENC + j];
  __syncthreads();
  if (threadIdx.x == 0) {
    float gi = gates[0], gf = gates[1], gg = gates[2], go = gates[3];
    float cn = xla_sigmoid(gf) * c_in[j] + xla_sigmoid(gi) * xla_tanh(gg);
    float hn = xla_sigmoid(go) * xla_tanh(cn);
    c_out[j] = cn;
    h_out[j] = hn;
  }
}

// Per-card logit + Gumbel score; per-wave argmax partials + online logsumexp.
__global__ void sims_kernel(const float* __restrict__ cards,
                            const float* __restrict__ eos,
                            const float* __restrict__ proj,
                            int ncards, uint32_t ka, uint32_t kb,
                            const int* __restrict__ takenList,
                            float* __restrict__ oScore, int* __restrict__ oIdx,
                            float* __restrict__ oLogit, float* __restrict__ oM,
                            float* __restrict__ oS) {
  int tid = blockIdx.x * blockDim.x + threadIdx.x;
  int wave = tid >> 6;
  int lane = tid & 63;
  int nwav = (gridDim.x * blockDim.x) >> 6;

  const float4* pv = (const float4*)proj;
  float4 p0 = pv[lane * 2 + 0];
  float4 p1 = pv[lane * 2 + 1];

  int t0 = takenList[0], t1 = takenList[1], t2 = takenList[2],
      t3 = takenList[3], t4 = takenList[4];

  float bS = -INFINITY; int bI = 0x7FFFFFFF; float bL = 0.0f;
  float m = -INFINITY, s = 0.0f;

  for (int i = wave; i <= ncards; i += nwav) {   // i == ncards -> EOS row
    const float* rowp = (i < ncards) ? (cards + (size_t)i * ENC) : eos;
    const float4* er = (const float4*)rowp;
    float4 e0 = er[lane * 2 + 0];
    float4 e1 = er[lane * 2 + 1];
    float acc = p0.x * e0.x + p0.y * e0.y + p0.z * e0.z + p0.w * e0.w +
                p1.x * e1.x + p1.y * e1.y + p1.z * e1.z + p1.w * e1.w;
#pragma unroll
    for (int k = 1; k < 64; k <<= 1) acc += __shfl_xor(acc, k, 64);
    // all 64 lanes now hold the full (identical) logit

    bool masked = (i < ncards) &&
                  (i == t0 || i == t1 || i == t2 || i == t3 || i == t4);
    if (!masked) {
      // online logsumexp over unmasked logits
      if (acc > m) { s = s * expf(m - acc) + 1.0f; m = acc; }
      else         { s += expf(acc - m); }
      // JAX partitionable random bits for index i: out0 ^ out1 of tf(key,(0,i))
      uint32_t r0, r1;
      tf2x32(ka, kb, 0u, (uint32_t)i, r0, r1);
      uint32_t bits = r0 ^ r1;
      float f = __uint_as_float((bits >> 9) | 0x3F800000u) - 1.0f;  // [0,1)
      float u = (f == 0.0f) ? 1.17549435e-38f : f;                  // minval=FLT_MIN
      float gmb = -logf(-logf(u));
      float score = gmb + acc;
      if (score > bS || (score == bS && i < bI)) { bS = score; bI = i; bL = acc; }
    }
  }
  if (lane == 0) {
    oScore[wave] = bS; oIdx[wave] = bI; oLogit[wave] = bL;
    oM[wave] = m; oS[wave] = s;
  }
}

// Merge partials; update selection state; write x = all_emb[idx].
__global__ void finalize_kernel(int nw, int step, int ncards,
                                const float* __restrict__ pScore, const int* __restrict__ pIdx,
                                const float* __restrict__ pLogit, const float* __restrict__ pM,
                                const float* __restrict__ pS,
                                const float* __restrict__ cards, const float* __restrict__ eos,
                                SelState* st, float* __restrict__ xout) {
  __shared__ float sS[256]; __shared__ int sI[256]; __shared__ float sL[256];
  __shared__ float sM[256]; __shared__ float sU[256];
  __shared__ int selIdx;
  int t = threadIdx.x;
  float bS = -INFINITY; int bI = 0x7FFFFFFF; float bL = 0.0f;
  float m = -INFINITY, s = 0.0f;
  for (int i = t; i < nw; i += 256) {
    float cs = pScore[i]; int ci = pIdx[i];
    if (cs > bS || (cs == bS && ci < bI)) { bS = cs; bI = ci; bL = pLogit[i]; }
    float cm = pM[i], cu = pS[i];
    if (cm > m) { s = s * expf(m - cm) + cu; m = cm; }
    else if (cm > -INFINITY) { s += cu * expf(cm - m); }
  }
  sS[t] = bS; sI[t] = bI; sL[t] = bL; sM[t] = m; sU[t] = s;
  __syncthreads();
  for (int off = 128; off > 0; off >>= 1) {
    if (t < off) {
      float cs = sS[t + off]; int ci = sI[t + off];
      if (cs > sS[t] || (cs == sS[t] && ci < sI[t])) {
        sS[t] = cs; sI[t] = ci; sL[t] = sL[t + off];
      }
      float cm = sM[t + off], cu = sU[t + off];
      if (cm > sM[t]) { sU[t] = sU[t] * expf(sM[t] - cm) + cu; sM[t] = cm; }
      else if (cm > -INFINITY) { sU[t] += cu * expf(cm - sM[t]); }
    }
    __syncthreads();
  }
  if (t == 0) {
    int idx = sI[0];
    float lse = sM[0] + logf(sU[0]);
    float log_prob = sL[0] - lse;
    int active = st->active;
    if (active) st->tlp += log_prob;
    int is_eos = (idx == ncards);
    int take = active && !is_eos;
    st->outIdx[step] = take ? idx : -1;
    if (take) st->taken[st->takenCount++] = idx;
    st->active = active && !is_eos;
    selIdx = idx;
  }
  __syncthreads();
  int idx = selIdx;
  const float* row = (idx < ncards) ? (cards + (size_t)idx * ENC) : eos;
  for (int e = t; e < ENC; e += 256) xout[e] = row[e];
}

__global__ void writeout_kernel(const SelState* st, float* __restrict__ out) {
  int t = threadIdx.x;
  if (t < NSTEPS) out[t] = (float)st->outIdx[t];
  if (t == NSTEPS) out[NSTEPS] = st->tlp;
}

// ---------------- host ----------------
extern "C" void kernel_launch(void* const* d_in, const int* in_sizes, int n_in,
                              void* d_out, int out_size, void* d_ws, size_t ws_size,
                              hipStream_t stream) {
  const float* ctx    = (const float*)d_in[0];
  const float* cards  = (const float*)d_in[1];
  const float* eos    = (const float*)d_in[2];
  const float* ctx_w  = (const float*)d_in[3];
  const float* ctx_b  = (const float*)d_in[4];
  const float* out_w  = (const float*)d_in[5];
  const float* out_b  = (const float*)d_in[6];
  const float* w_ih_0 = (const float*)d_in[7];
  const float* w_hh_0 = (const float*)d_in[8];
  const float* b_ih_0 = (const float*)d_in[9];
  const float* b_hh_0 = (const float*)d_in[10];
  const float* w_ih_1 = (const float*)d_in[11];
  const float* w_hh_1 = (const float*)d_in[12];
  const float* b_ih_1 = (const float*)d_in[13];
  const float* b_hh_1 = (const float*)d_in[14];
  int ncards = in_sizes[1] / ENC;   // 100000

  // workspace carve
  float* Z     = (float*)d_ws;          // 512 zeros
  float* xbuf  = Z + ENC;
  float* projb = xbuf + ENC;
  float* h0A = projb + ENC; float* c0A = h0A + ENC;
  float* h1A = c0A + ENC;   float* c1A = h1A + ENC;
  float* h0B = c1A + ENC;   float* c0B = h0B + ENC;
  float* h1B = c0B + ENC;   float* c1B = h1B + ENC;
  SelState* st = (SelState*)(c1B + ENC);
  float* pScore = (float*)((char*)st + 256);
  int*   pIdx   = (int*)(pScore + NWAVES);
  float* pLogit = (float*)(pIdx + NWAVES);
  float* pM     = pLogit + NWAVES;
  float* pS     = pM + NWAVES;

  // keys = jax.random.split(jax.random.key(42), 5)  (partitionable/fold-like)
  uint32_t keys[NSTEPS][2];
  for (int s2 = 0; s2 < NSTEPS; ++s2)
    tf2x32(0u, 42u, 0u, (uint32_t)s2, keys[s2][0], keys[s2][1]);

  init_kernel<<<1, 512, 0, stream>>>(Z, st);

  // x0 = ctx @ ctx_w.T + ctx_b ; two LSTM steps from zero state
  matvec512<<<128, 256, 0, stream>>>(ctx_w, ctx_b, ctx, xbuf);
  lstm_step_kernel<<<512, 256, 0, stream>>>(w_ih_0, w_hh_0, b_ih_0, b_hh_0,
                                            xbuf, Z, Z, h0A, c0A);
  lstm_step_kernel<<<512, 256, 0, stream>>>(w_ih_1, w_hh_1, b_ih_1, b_hh_1,
                                            h0A, Z, Z, h1A, c1A);

  float *h0c = h0A, *c0c = c0A, *h1c = h1A, *c1c = c1A;
  float *h0n = h0B, *c0n = c0B, *h1n = h1B, *c1n = c1B;

  for (int s2 = 0; s2 < NSTEPS; ++s2) {
    matvec512<<<128, 256, 0, stream>>>(out_w, out_b, h1c, projb);
    sims_kernel<<<SIMS_BLOCKS, 256, 0, stream>>>(cards, eos, projb, ncards,
                                                 keys[s2][0], keys[s2][1],
                                                 (const int*)st,   // taken[] at offset 0
                                                 pScore, pIdx, pLogit, pM, pS);
    finalize_kernel<<<1, 256, 0, stream>>>(NWAVES, s2, ncards,
                                           pScore, pIdx, pLogit, pM, pS,
                                           cards, eos, st, xbuf);
    lstm_step_kernel<<<512, 256, 0, stream>>>(w_ih_0, w_hh_0, b_ih_0, b_hh_0,
                                              xbuf, h0c, c0c, h0n, c0n);
    lstm_step_kernel<<<512, 256, 0, stream>>>(w_ih_1, w_hh_1, b_ih_1, b_hh_1,
                                              h0n, h1c, c1c, h1n, c1n);
    float* tp;
    tp = h0c; h0c = h0n; h0n = tp;
    tp = c0c; c0c = c0n; c0n = tp;
    tp = h1c; h1c = h1n; h1n = tp;
    tp = c1c; c1c = c1n; c1n = tp;
  }

  writeout_kernel<<<1, 64, 0, stream>>>(st, (float*)d_out);
}